// Round 1
// baseline (972.923 us; speedup 1.0000x reference)
//
#include <hip/hip_runtime.h>
#include <cmath>

// ---------------------------------------------------------------------------
// RPN head post-processing (mmdet GetBboxes-style), exact-semantics HIP port.
//
// Correctness strategy: all ordering-critical math (sigmoid, delta2bbox, IoU,
// NMS threshold compares) is done in fp64 to match the harness's fp64 numpy
// reference ("ref=np"); within-level top-k ordering uses raw fp32 logit bits
// (monotone-equivalent to fp64 sigmoid ordering, exact ties -> lower index,
// matching lax.top_k / stable argsort).
// ---------------------------------------------------------------------------

#define NPRE 2000
#define NPOST 1000

static __device__ __forceinline__ unsigned int flipf_dev(float f) {
  unsigned int u = __float_as_uint(f);
  return (u & 0x80000000u) ? ~u : (u | 0x80000000u);
}
static __device__ __forceinline__ float unflipf_dev(unsigned int k) {
  unsigned int u = (k & 0x80000000u) ? (k ^ 0x80000000u) : ~k;
  return __uint_as_float(u);
}
static __device__ __forceinline__ unsigned long long flip64_dev(double d) {
  unsigned long long u = (unsigned long long)__double_as_longlong(d);
  return (u & 0x8000000000000000ull) ? ~u : (u | 0x8000000000000000ull);
}

struct RPNParams {
  const float* cls[5];
  const float* bbox[5];
  const float* anc[5];
  unsigned int* hist;          // [10][65536]
  unsigned int* mainCount;     // [10]
  unsigned int* candCount;     // [10]
  unsigned int* Bstar;         // [10]
  unsigned long long* mainEK;  // [10][2048]  packed (key<<32)|~idx
  unsigned long long* candEK;  // [10][8192]
  double* selBoxes;            // [10][2000][4]
  double* selScores;           // [10][2000]
  unsigned long long* mask;    // [10][2000][32]
  unsigned int* rowNZ;         // [10][2000]
  unsigned long long* keeps;   // [10][32]
  double* postScores;          // [10][1000]
  float* postBoxes;            // [10][1000][4]
  unsigned int* partial;       // [16][5000]
  float* out;                  // [2][1000][4]
};

__device__ __constant__ int c_NL[5]  = {201600, 50400, 12600, 3150, 819};
__device__ __constant__ int c_HW[5]  = {67200, 16800, 4200, 1050, 273};
// blocks-per-task for the 8 tasks with N>=2000 (levels 0..3 x 2 images)
__device__ __constant__ int c_BPT[8] = {50, 50, 13, 13, 4, 4, 1, 1};

static __device__ __forceinline__ void map_block(int bx, int& t, int& chunk) {
  int start = 0;
  t = 0;
  for (int k = 0; k < 8; k++) {
    if (bx < start + c_BPT[k]) { t = k; break; }
    start += c_BPT[k];
  }
  chunk = bx - start;
}

// --- 1. per-task 16-bit-bucket histogram of flipped logit keys --------------
__global__ void k_hist(RPNParams p) {
  int t, chunk;
  map_block(blockIdx.x, t, chunk);
  int l = t >> 1, b = t & 1;
  int N = c_NL[l], HW = c_HW[l];
  const float* cls = p.cls[l] + (size_t)b * 3 * HW;
  unsigned int* hist = p.hist + (size_t)t * 65536;
  int base = chunk * 4096 + threadIdx.x;
  for (int k = 0; k < 4; k++) {
    int n = base + k * 1024;
    if (n < N) {
      int a = n % 3, hw = n / 3;
      unsigned int key = flipf_dev(cls[a * HW + hw]);
      atomicAdd(&hist[key >> 16], 1u);
    }
  }
}

// --- 2. find threshold bucket B* per task (suffix-sum over 65536 buckets) ---
__global__ void k_find(RPNParams p) {
  int t = blockIdx.x;  // 0..7
  unsigned int* hist = p.hist + (size_t)t * 65536;
  __shared__ unsigned int S[1024];
  __shared__ int gsel;
  __shared__ unsigned int baseAbove;
  int g = threadIdx.x;
  unsigned int s = 0;
  for (int j = 0; j < 64; j++) s += hist[g * 64 + j];
  S[g] = s;
  __syncthreads();
  for (int off = 1; off < 1024; off <<= 1) {
    unsigned int add = (g + off < 1024) ? S[g + off] : 0u;
    __syncthreads();
    S[g] += add;
    __syncthreads();
  }
  const unsigned int need = NPRE;
  if (S[g] >= need && (g == 1023 || S[g + 1] < need)) {
    gsel = g;
    baseAbove = (g == 1023) ? 0u : S[g + 1];
  }
  __syncthreads();
  if (threadIdx.x == 0) {
    int gg = gsel;
    unsigned int c = baseAbove;
    int bstar = gg * 64;
    for (int bb = gg * 64 + 63; bb >= gg * 64; bb--) {
      c += hist[bb];
      if (c >= need) { bstar = bb; break; }
    }
    p.Bstar[t] = (unsigned int)bstar;
  }
}

// --- 3. compaction: strictly-above bucket -> main list, == bucket -> cand ---
__global__ void k_compact(RPNParams p) {
  int t, chunk;
  map_block(blockIdx.x, t, chunk);
  int l = t >> 1, b = t & 1;
  int N = c_NL[l], HW = c_HW[l];
  const float* cls = p.cls[l] + (size_t)b * 3 * HW;
  unsigned int Bs = p.Bstar[t];
  int base = chunk * 4096 + threadIdx.x;
  for (int k = 0; k < 4; k++) {
    int n = base + k * 1024;
    if (n < N) {
      int a = n % 3, hw = n / 3;
      unsigned int key = flipf_dev(cls[a * HW + hw]);
      unsigned int hi = key >> 16;
      unsigned long long ek =
          ((unsigned long long)key << 32) | (unsigned int)(~(unsigned int)n);
      if (hi > Bs) {
        unsigned int pos = atomicAdd(&p.mainCount[t], 1u);
        if (pos < 2048u) p.mainEK[(size_t)t * 2048 + pos] = ek;
      } else if (hi == Bs) {
        unsigned int pos = atomicAdd(&p.candCount[t], 1u);
        if (pos < 8192u) p.candEK[(size_t)t * 8192 + pos] = ek;
      }
    }
  }
}

// --- 4. assemble exact top-2000, counting-rank sort, fp64 decode ------------
__global__ void k_assemble(RPNParams p) {
  int t = blockIdx.x;  // 0..9
  int l = t >> 1, b = t & 1;
  int N = c_NL[l], HW = c_HW[l];
  __shared__ unsigned long long ekA[2048];
  __shared__ unsigned long long srt[2048];
  int tid = threadIdx.x;

  if (N >= NPRE) {
    unsigned int cGT = min(p.mainCount[t], 2000u);
    unsigned int nC = min(p.candCount[t], 8192u);
    unsigned int needIn = 2000u - cGT;
    for (unsigned int m = tid; m < cGT; m += 1024)
      ekA[m] = p.mainEK[(size_t)t * 2048 + m];
    const unsigned long long* cek = p.candEK + (size_t)t * 8192;
    for (unsigned int e = tid; e < nC; e += 1024) {
      unsigned long long ve = cek[e];
      unsigned int r = 0;
      for (unsigned int j = 0; j < nC; j++) r += (cek[j] > ve) ? 1u : 0u;
      if (r < needIn) ekA[cGT + r] = ve;
    }
    for (unsigned int r = 2000u + tid; r < 2048u; r += 1024)
      ekA[r] = (unsigned long long)(unsigned int)(~r);  // key=0 pads, idx=r
  } else {
    // level 4: reference pads to 2000 with score=-1, zero deltas/anchors,
    // top_i = arange. NMS's argsort sorts; equivalent to our key sort with
    // pad key = 0 (below all finite logits) and idx = position.
    const float* cls = p.cls[l] + (size_t)b * 3 * HW;
    for (int r = tid; r < 2048; r += 1024) {
      if (r < N) {
        int a = r % 3, hw = r / 3;
        unsigned int key = flipf_dev(cls[a * HW + hw]);
        ekA[r] = ((unsigned long long)key << 32) |
                 (unsigned int)(~(unsigned int)r);
      } else {
        ekA[r] = (unsigned long long)(unsigned int)(~(unsigned int)r);
      }
    }
  }
  __syncthreads();

  // counting-rank sort (desc by key, asc by idx; packed u64 compare).
  {
    unsigned long long v0 = ekA[tid], v1 = ekA[tid + 1024];
    int r0 = 0, r1 = 0;
    for (int j = 0; j < 2048; j++) {
      unsigned long long vj = ekA[j];
      r0 += (vj > v0) ? 1 : 0;
      r1 += (vj > v1) ? 1 : 0;
    }
    srt[r0] = v0;
    srt[r1] = v1;
  }
  __syncthreads();

  const double RCLIP = fabs(log(16.0 / 1000.0));  // mmdet wh_ratio_clip
  const float* bbx = p.bbox[l] + (size_t)b * 12 * HW;
  const float* anc = p.anc[l];
  for (int r = tid; r < NPRE; r += 1024) {
    unsigned long long v = srt[r];
    unsigned int key = (unsigned int)(v >> 32);
    double* SB = p.selBoxes + ((size_t)t * NPRE + r) * 4;
    if (key == 0u) {  // pad: zero anchors/deltas -> zero box, score -1
      SB[0] = 0.0; SB[1] = 0.0; SB[2] = 0.0; SB[3] = 0.0;
      p.selScores[(size_t)t * NPRE + r] = -1.0;
    } else {
      unsigned int idx = ~(unsigned int)(v & 0xFFFFFFFFull);
      int a = (int)(idx % 3u);
      int hw = (int)(idx / 3u);
      double d0 = (double)bbx[(a * 4 + 0) * HW + hw];
      double d1 = (double)bbx[(a * 4 + 1) * HW + hw];
      double d2 = (double)bbx[(a * 4 + 2) * HW + hw];
      double d3 = (double)bbx[(a * 4 + 3) * HW + hw];
      double a0 = (double)anc[(size_t)idx * 4 + 0];
      double a1 = (double)anc[(size_t)idx * 4 + 1];
      double a2 = (double)anc[(size_t)idx * 4 + 2];
      double a3 = (double)anc[(size_t)idx * 4 + 3];
      double dw = fmin(fmax(d2, -RCLIP), RCLIP);
      double dh = fmin(fmax(d3, -RCLIP), RCLIP);
      double pw = a2 - a0, ph = a3 - a1;
      double px = (a0 + a2) * 0.5, py = (a1 + a3) * 0.5;
      double gw = pw * exp(dw), gh = ph * exp(dh);
      double gx = px + pw * d0, gy = py + ph * d1;
      double x1 = fmin(fmax(gx - 0.5 * gw, 0.0), 1344.0);
      double y1 = fmin(fmax(gy - 0.5 * gh, 0.0), 800.0);
      double x2 = fmin(fmax(gx + 0.5 * gw, 0.0), 1344.0);
      double y2 = fmin(fmax(gy + 0.5 * gh, 0.0), 800.0);
      SB[0] = x1; SB[1] = y1; SB[2] = x2; SB[3] = y2;
      float f = unflipf_dev(key);
      p.selScores[(size_t)t * NPRE + r] = 1.0 / (1.0 + exp(-(double)f));
    }
  }
}

// --- 5. fp64 pairwise IoU -> suppression bitmask (upper triangle) -----------
__global__ void k_iou(RPNParams p) {
  int bx = blockIdx.x;
  int t = bx / 20;
  int r0 = (bx % 20) * 100;
  __shared__ double X1[2000], Y1[2000], X2[2000], Y2[2000];
  const double* SB = p.selBoxes + (size_t)t * NPRE * 4;
  for (int i = threadIdx.x; i < NPRE; i += 256) {
    X1[i] = SB[i * 4 + 0]; Y1[i] = SB[i * 4 + 1];
    X2[i] = SB[i * 4 + 2]; Y2[i] = SB[i * 4 + 3];
  }
  __syncthreads();
  int wave = threadIdx.x >> 6, lane = threadIdx.x & 63;
  for (int i = r0 + wave; i < r0 + 100; i += 4) {
    double x1i = X1[i], y1i = Y1[i], x2i = X2[i], y2i = Y2[i];
    double ai = (x2i - x1i) * (y2i - y1i);
    unsigned int nz = 0;
    for (int k = 0; k < 32; k++) {
      int j = k * 64 + lane;
      bool pred = false;
      if (j > i && j < NPRE) {
        double x1j = X1[j], y1j = Y1[j], x2j = X2[j], y2j = Y2[j];
        double aj = (x2j - x1j) * (y2j - y1j);
        double lx = fmax(x1i, x1j), ly = fmax(y1i, y1j);
        double rx = fmin(x2i, x2j), ry = fmin(y2i, y2j);
        double w = fmax(rx - lx, 0.0), h = fmax(ry - ly, 0.0);
        double inter = w * h;
        double uni = ai + aj - inter;
        double iou = inter / fmax(uni, 1e-6);
        pred = iou > 0.7;
      }
      unsigned long long word = __ballot(pred);
      if (lane == 0) p.mask[((size_t)t * NPRE + i) * 32 + k] = word;
      nz |= (word ? 1u : 0u) << k;
    }
    if (lane == 0) p.rowNZ[(size_t)t * NPRE + i] = nz;
  }
}

// --- 6. greedy NMS scan, chunked 64-wide, 1 wave per task -------------------
__global__ void k_greedy(RPNParams p) {
  int t = blockIdx.x;
  int lane = threadIdx.x;  // 64 threads
  __shared__ unsigned long long lm[64 * 32];
  __shared__ unsigned int lnz[64];
  unsigned long long suppw = 0ull, keepw = 0ull;
  const unsigned long long* MK = p.mask + (size_t)t * NPRE * 32;
  const unsigned int* NZ = p.rowNZ + (size_t)t * NPRE;
  for (int c = 0; c < 32; c++) {
    int i = c * 64 + lane;
    unsigned int nz = 0;
    if (i < NPRE) nz = NZ[i] & (0xFFFFFFFFu << c);
    lnz[lane] = nz;
    unsigned int tmp = nz;
    while (tmp) {
      int w = __ffs(tmp) - 1;
      tmp &= tmp - 1;
      lm[lane * 32 + w] = MK[(size_t)i * 32 + w];
    }
    __syncthreads();
    unsigned long long sc = __shfl(suppw, c);
    unsigned long long kc = 0ull;
    int lim = min(64, NPRE - c * 64);
    for (int t2 = 0; t2 < lim; t2++) {
      if (!((sc >> t2) & 1ull)) {
        kc |= 1ull << t2;
        if ((lnz[t2] >> c) & 1u) sc |= lm[t2 * 32 + c];
      }
    }
    if (lane == c) { suppw = sc; keepw = kc; }
    if (lane > c && lane < 32) {
      for (int t2 = 0; t2 < lim; t2++) {
        if (((kc >> t2) & 1ull) && ((lnz[t2] >> lane) & 1u))
          suppw |= lm[t2 * 32 + lane];
      }
    }
    __syncthreads();
  }
  if (lane < 32) p.keeps[(size_t)t * 32 + lane] = keepw;
}

// --- 7. per-task re-rank: kept(+score) first (idx order), then -1 group -----
__global__ void k_post(RPNParams p) {
  int t = blockIdx.x;
  __shared__ unsigned long long kw[32], aw[32], bw[32];
  __shared__ unsigned int prefA[33], prefB[33];
  int tid = threadIdx.x;  // 256
  if (tid < 32) kw[tid] = p.keeps[(size_t)t * 32 + tid];
  __syncthreads();
  int wave = tid >> 6, lane = tid & 63;
  for (int ch = wave; ch < 32; ch += 4) {
    int i = ch * 64 + lane;
    bool inr = i < NPRE;
    bool kb = inr && ((kw[ch] >> lane) & 1ull);
    bool A = kb && (inr ? (p.selScores[(size_t)t * NPRE + i] > -0.5) : false);
    bool B = inr && !A;
    unsigned long long wa = __ballot(A);
    unsigned long long wb = __ballot(B);
    if (lane == 0) { aw[ch] = wa; bw[ch] = wb; }
  }
  __syncthreads();
  if (tid == 0) {
    unsigned int ca = 0, cb = 0;
    for (int w = 0; w < 32; w++) {
      prefA[w] = ca; ca += __popcll(aw[w]);
      prefB[w] = cb; cb += __popcll(bw[w]);
    }
    prefA[32] = ca; prefB[32] = cb;
  }
  __syncthreads();
  unsigned int KA = prefA[32];
  for (int i = tid; i < NPRE; i += 256) {
    int w = i >> 6, bpos = i & 63;
    unsigned long long below = (bpos == 0) ? 0ull : (~0ull >> (64 - bpos));
    bool kb = (kw[w] >> bpos) & 1ull;
    double s = p.selScores[(size_t)t * NPRE + i];
    bool A = kb && (s > -0.5);
    unsigned int slot;
    double outs;
    if (A) {
      slot = prefA[w] + (unsigned int)__popcll(aw[w] & below);
      outs = s;
    } else {
      slot = KA + prefB[w] + (unsigned int)__popcll(bw[w] & below);
      outs = -1.0;
    }
    if (slot < NPOST) {
      p.postScores[(size_t)t * NPOST + slot] = outs;
      const double* SB = p.selBoxes + ((size_t)t * NPRE + i) * 4;
      float* PB = p.postBoxes + ((size_t)t * NPOST + slot) * 4;
      PB[0] = (float)SB[0]; PB[1] = (float)SB[1];
      PB[2] = (float)SB[2]; PB[3] = (float)SB[3];
    }
  }
}

// --- 8a. final cross-level top-1000: sliced counting-rank -------------------
__global__ void k_finalA(RPNParams p) {
  int b = blockIdx.x >> 3;
  int s = blockIdx.x & 7;
  int j0 = s * 625;
  __shared__ unsigned long long kj[625];
  int tid = threadIdx.x;  // 1024
  for (int j = tid; j < 625; j += 1024) {
    int e = j0 + j;
    int l = e / 1000, slot = e % 1000;
    int t = l * 2 + b;
    kj[j] = flip64_dev(p.postScores[(size_t)t * NPOST + slot]);
  }
  __syncthreads();
  for (int e = tid; e < 5000; e += 1024) {
    int l = e / 1000, slot = e % 1000;
    int t = l * 2 + b;
    unsigned long long ke = flip64_dev(p.postScores[(size_t)t * NPOST + slot]);
    unsigned int r = 0;
    for (int j = 0; j < 625; j++) {
      unsigned long long v = kj[j];
      int jg = j0 + j;
      r += (v > ke || (v == ke && jg < e)) ? 1u : 0u;
    }
    p.partial[((size_t)b * 8 + s) * 5000 + e] = r;
  }
}

// --- 8b. reduce ranks, gather output boxes ----------------------------------
__global__ void k_finalB(RPNParams p) {
  int b = blockIdx.x;
  int tid = threadIdx.x;
  for (int e = tid; e < 5000; e += 1024) {
    unsigned int r = 0;
    for (int s = 0; s < 8; s++) r += p.partial[((size_t)b * 8 + s) * 5000 + e];
    if (r < NPOST) {
      int l = e / 1000, slot = e % 1000;
      int t = l * 2 + b;
      const float* PB = p.postBoxes + ((size_t)t * NPOST + slot) * 4;
      float* O = p.out + ((size_t)b * NPOST + r) * 4;
      O[0] = PB[0]; O[1] = PB[1]; O[2] = PB[2]; O[3] = PB[3];
    }
  }
}

extern "C" void kernel_launch(void* const* d_in, const int* in_sizes, int n_in,
                              void* d_out, int out_size, void* d_ws,
                              size_t ws_size, hipStream_t stream) {
  RPNParams p;
  // setup_inputs() dict order is interleaved (cls_i, bbox_i, anc_i per level);
  // detect defensively vs grouped order via in_sizes.
  bool interleaved = (n_in >= 2) && (in_sizes[1] == 4 * in_sizes[0]);
  for (int l = 0; l < 5; l++) {
    if (interleaved) {
      p.cls[l]  = (const float*)d_in[3 * l + 0];
      p.bbox[l] = (const float*)d_in[3 * l + 1];
      p.anc[l]  = (const float*)d_in[3 * l + 2];
    } else {
      p.cls[l]  = (const float*)d_in[l];
      p.bbox[l] = (const float*)d_in[5 + l];
      p.anc[l]  = (const float*)d_in[10 + l];
    }
  }
  char* w = (char*)d_ws;
  size_t off = 0;
  auto alloc = [&](size_t bytes) {
    off = (off + 255) & ~(size_t)255;
    void* r = w + off;
    off += bytes;
    return r;
  };
  p.hist      = (unsigned int*)alloc((size_t)10 * 65536 * 4);
  p.mainCount = (unsigned int*)alloc(10 * 4);
  p.candCount = (unsigned int*)alloc(10 * 4);
  size_t zbytes = off;  // zeroed region: hist + atomic counters
  p.Bstar      = (unsigned int*)alloc(10 * 4);
  p.mainEK     = (unsigned long long*)alloc((size_t)10 * 2048 * 8);
  p.candEK     = (unsigned long long*)alloc((size_t)10 * 8192 * 8);
  p.selBoxes   = (double*)alloc((size_t)10 * NPRE * 4 * 8);
  p.selScores  = (double*)alloc((size_t)10 * NPRE * 8);
  p.mask       = (unsigned long long*)alloc((size_t)10 * NPRE * 32 * 8);
  p.rowNZ      = (unsigned int*)alloc((size_t)10 * NPRE * 4);
  p.keeps      = (unsigned long long*)alloc((size_t)10 * 32 * 8);
  p.postScores = (double*)alloc((size_t)10 * NPOST * 8);
  p.postBoxes  = (float*)alloc((size_t)10 * NPOST * 4 * 4);
  p.partial    = (unsigned int*)alloc((size_t)16 * 5000 * 4);
  p.out = (float*)d_out;
  (void)ws_size; (void)out_size;

  hipMemsetAsync(d_ws, 0, zbytes, stream);
  k_hist<<<dim3(136), dim3(1024), 0, stream>>>(p);
  k_find<<<dim3(8), dim3(1024), 0, stream>>>(p);
  k_compact<<<dim3(136), dim3(1024), 0, stream>>>(p);
  k_assemble<<<dim3(10), dim3(1024), 0, stream>>>(p);
  k_iou<<<dim3(200), dim3(256), 0, stream>>>(p);
  k_greedy<<<dim3(10), dim3(64), 0, stream>>>(p);
  k_post<<<dim3(10), dim3(256), 0, stream>>>(p);
  k_finalA<<<dim3(16), dim3(1024), 0, stream>>>(p);
  k_finalB<<<dim3(2), dim3(1024), 0, stream>>>(p);
}

// Round 2
// 871.836 us; speedup vs baseline: 1.1159x; 1.1159x over previous
//
#include <hip/hip_runtime.h>
#include <cmath>

// ---------------------------------------------------------------------------
// RPN head post-processing (mmdet GetBboxes-style), exact-semantics HIP port.
//
// Correctness strategy: all ordering-critical math (sigmoid, delta2bbox, IoU,
// NMS threshold compares) is done in fp64 to match the harness's fp64 numpy
// reference ("ref=np"); within-level top-k ordering uses raw fp32 logit bits
// (monotone-equivalent to fp64 sigmoid ordering, exact ties -> lower index,
// matching lax.top_k / stable argsort).
//
// R1: k_greedy rewritten register-resident (was 338us latency-serialized:
// 2048 dependent LDS reads + serial global mask walk). Self-chunk 64x64
// submatrix lives in 128 VGPRs/lane; closure is a pure VALU chain; cross-
// chunk apply batches 8 mask loads in flight. k_iou: fp64 divide replaced
// by cross-multiplied compare + exact-div fallback inside 1e-9 band.
// ---------------------------------------------------------------------------

#define NPRE 2000
#define NPOST 1000

static __device__ __forceinline__ unsigned int flipf_dev(float f) {
  unsigned int u = __float_as_uint(f);
  return (u & 0x80000000u) ? ~u : (u | 0x80000000u);
}
static __device__ __forceinline__ float unflipf_dev(unsigned int k) {
  unsigned int u = (k & 0x80000000u) ? (k ^ 0x80000000u) : ~k;
  return __uint_as_float(u);
}
static __device__ __forceinline__ unsigned long long flip64_dev(double d) {
  unsigned long long u = (unsigned long long)__double_as_longlong(d);
  return (u & 0x8000000000000000ull) ? ~u : (u | 0x8000000000000000ull);
}

struct RPNParams {
  const float* cls[5];
  const float* bbox[5];
  const float* anc[5];
  unsigned int* hist;          // [10][65536]
  unsigned int* mainCount;     // [10]
  unsigned int* candCount;     // [10]
  unsigned int* Bstar;         // [10]
  unsigned long long* mainEK;  // [10][2048]  packed (key<<32)|~idx
  unsigned long long* candEK;  // [10][8192]
  double* selBoxes;            // [10][2000][4]
  double* selScores;           // [10][2000]
  unsigned long long* mask;    // [10][2000][32]
  unsigned int* rowNZ;         // [10][2000]
  unsigned long long* keeps;   // [10][32]
  double* postScores;          // [10][1000]
  float* postBoxes;            // [10][1000][4]
  unsigned int* partial;       // [16][5000]
  float* out;                  // [2][1000][4]
};

__device__ __constant__ int c_NL[5]  = {201600, 50400, 12600, 3150, 819};
__device__ __constant__ int c_HW[5]  = {67200, 16800, 4200, 1050, 273};
// blocks-per-task for the 8 tasks with N>=2000 (levels 0..3 x 2 images)
__device__ __constant__ int c_BPT[8] = {50, 50, 13, 13, 4, 4, 1, 1};

static __device__ __forceinline__ void map_block(int bx, int& t, int& chunk) {
  int start = 0;
  t = 0;
  for (int k = 0; k < 8; k++) {
    if (bx < start + c_BPT[k]) { t = k; break; }
    start += c_BPT[k];
  }
  chunk = bx - start;
}

// --- 1. per-task 16-bit-bucket histogram of flipped logit keys --------------
__global__ void k_hist(RPNParams p) {
  int t, chunk;
  map_block(blockIdx.x, t, chunk);
  int l = t >> 1, b = t & 1;
  int N = c_NL[l], HW = c_HW[l];
  const float* cls = p.cls[l] + (size_t)b * 3 * HW;
  unsigned int* hist = p.hist + (size_t)t * 65536;
  int base = chunk * 4096 + threadIdx.x;
  for (int k = 0; k < 4; k++) {
    int n = base + k * 1024;
    if (n < N) {
      int a = n % 3, hw = n / 3;
      unsigned int key = flipf_dev(cls[a * HW + hw]);
      atomicAdd(&hist[key >> 16], 1u);
    }
  }
}

// --- 2. find threshold bucket B* per task (suffix-sum over 65536 buckets) ---
__global__ void k_find(RPNParams p) {
  int t = blockIdx.x;  // 0..7
  unsigned int* hist = p.hist + (size_t)t * 65536;
  __shared__ unsigned int S[1024];
  __shared__ int gsel;
  __shared__ unsigned int baseAbove;
  int g = threadIdx.x;
  unsigned int s = 0;
  for (int j = 0; j < 64; j++) s += hist[g * 64 + j];
  S[g] = s;
  __syncthreads();
  for (int off = 1; off < 1024; off <<= 1) {
    unsigned int add = (g + off < 1024) ? S[g + off] : 0u;
    __syncthreads();
    S[g] += add;
    __syncthreads();
  }
  const unsigned int need = NPRE;
  if (S[g] >= need && (g == 1023 || S[g + 1] < need)) {
    gsel = g;
    baseAbove = (g == 1023) ? 0u : S[g + 1];
  }
  __syncthreads();
  if (threadIdx.x == 0) {
    int gg = gsel;
    unsigned int c = baseAbove;
    int bstar = gg * 64;
    for (int bb = gg * 64 + 63; bb >= gg * 64; bb--) {
      c += hist[bb];
      if (c >= need) { bstar = bb; break; }
    }
    p.Bstar[t] = (unsigned int)bstar;
  }
}

// --- 3. compaction: strictly-above bucket -> main list, == bucket -> cand ---
__global__ void k_compact(RPNParams p) {
  int t, chunk;
  map_block(blockIdx.x, t, chunk);
  int l = t >> 1, b = t & 1;
  int N = c_NL[l], HW = c_HW[l];
  const float* cls = p.cls[l] + (size_t)b * 3 * HW;
  unsigned int Bs = p.Bstar[t];
  int base = chunk * 4096 + threadIdx.x;
  for (int k = 0; k < 4; k++) {
    int n = base + k * 1024;
    if (n < N) {
      int a = n % 3, hw = n / 3;
      unsigned int key = flipf_dev(cls[a * HW + hw]);
      unsigned int hi = key >> 16;
      unsigned long long ek =
          ((unsigned long long)key << 32) | (unsigned int)(~(unsigned int)n);
      if (hi > Bs) {
        unsigned int pos = atomicAdd(&p.mainCount[t], 1u);
        if (pos < 2048u) p.mainEK[(size_t)t * 2048 + pos] = ek;
      } else if (hi == Bs) {
        unsigned int pos = atomicAdd(&p.candCount[t], 1u);
        if (pos < 8192u) p.candEK[(size_t)t * 8192 + pos] = ek;
      }
    }
  }
}

// --- 4. assemble exact top-2000, counting-rank sort, fp64 decode ------------
__global__ void k_assemble(RPNParams p) {
  int t = blockIdx.x;  // 0..9
  int l = t >> 1, b = t & 1;
  int N = c_NL[l], HW = c_HW[l];
  __shared__ unsigned long long ekA[2048];
  __shared__ unsigned long long srt[2048];
  int tid = threadIdx.x;

  if (N >= NPRE) {
    unsigned int cGT = min(p.mainCount[t], 2000u);
    unsigned int nC = min(p.candCount[t], 8192u);
    unsigned int needIn = 2000u - cGT;
    for (unsigned int m = tid; m < cGT; m += 1024)
      ekA[m] = p.mainEK[(size_t)t * 2048 + m];
    const unsigned long long* cek = p.candEK + (size_t)t * 8192;
    for (unsigned int e = tid; e < nC; e += 1024) {
      unsigned long long ve = cek[e];
      unsigned int r = 0;
      for (unsigned int j = 0; j < nC; j++) r += (cek[j] > ve) ? 1u : 0u;
      if (r < needIn) ekA[cGT + r] = ve;
    }
    for (unsigned int r = 2000u + tid; r < 2048u; r += 1024)
      ekA[r] = (unsigned long long)(unsigned int)(~r);  // key=0 pads, idx=r
  } else {
    // level 4: reference pads to 2000 with score=-1, zero deltas/anchors,
    // top_i = arange. NMS's argsort sorts; equivalent to our key sort with
    // pad key = 0 (below all finite logits) and idx = position.
    const float* cls = p.cls[l] + (size_t)b * 3 * HW;
    for (int r = tid; r < 2048; r += 1024) {
      if (r < N) {
        int a = r % 3, hw = r / 3;
        unsigned int key = flipf_dev(cls[a * HW + hw]);
        ekA[r] = ((unsigned long long)key << 32) |
                 (unsigned int)(~(unsigned int)r);
      } else {
        ekA[r] = (unsigned long long)(unsigned int)(~(unsigned int)r);
      }
    }
  }
  __syncthreads();

  // counting-rank sort (desc by key, asc by idx; packed u64 compare).
  {
    unsigned long long v0 = ekA[tid], v1 = ekA[tid + 1024];
    int r0 = 0, r1 = 0;
    for (int j = 0; j < 2048; j++) {
      unsigned long long vj = ekA[j];
      r0 += (vj > v0) ? 1 : 0;
      r1 += (vj > v1) ? 1 : 0;
    }
    srt[r0] = v0;
    srt[r1] = v1;
  }
  __syncthreads();

  const double RCLIP = fabs(log(16.0 / 1000.0));  // mmdet wh_ratio_clip
  const float* bbx = p.bbox[l] + (size_t)b * 12 * HW;
  const float* anc = p.anc[l];
  for (int r = tid; r < NPRE; r += 1024) {
    unsigned long long v = srt[r];
    unsigned int key = (unsigned int)(v >> 32);
    double* SB = p.selBoxes + ((size_t)t * NPRE + r) * 4;
    if (key == 0u) {  // pad: zero anchors/deltas -> zero box, score -1
      SB[0] = 0.0; SB[1] = 0.0; SB[2] = 0.0; SB[3] = 0.0;
      p.selScores[(size_t)t * NPRE + r] = -1.0;
    } else {
      unsigned int idx = ~(unsigned int)(v & 0xFFFFFFFFull);
      int a = (int)(idx % 3u);
      int hw = (int)(idx / 3u);
      double d0 = (double)bbx[(a * 4 + 0) * HW + hw];
      double d1 = (double)bbx[(a * 4 + 1) * HW + hw];
      double d2 = (double)bbx[(a * 4 + 2) * HW + hw];
      double d3 = (double)bbx[(a * 4 + 3) * HW + hw];
      double a0 = (double)anc[(size_t)idx * 4 + 0];
      double a1 = (double)anc[(size_t)idx * 4 + 1];
      double a2 = (double)anc[(size_t)idx * 4 + 2];
      double a3 = (double)anc[(size_t)idx * 4 + 3];
      double dw = fmin(fmax(d2, -RCLIP), RCLIP);
      double dh = fmin(fmax(d3, -RCLIP), RCLIP);
      double pw = a2 - a0, ph = a3 - a1;
      double px = (a0 + a2) * 0.5, py = (a1 + a3) * 0.5;
      double gw = pw * exp(dw), gh = ph * exp(dh);
      double gx = px + pw * d0, gy = py + ph * d1;
      double x1 = fmin(fmax(gx - 0.5 * gw, 0.0), 1344.0);
      double y1 = fmin(fmax(gy - 0.5 * gh, 0.0), 800.0);
      double x2 = fmin(fmax(gx + 0.5 * gw, 0.0), 1344.0);
      double y2 = fmin(fmax(gy + 0.5 * gh, 0.0), 800.0);
      SB[0] = x1; SB[1] = y1; SB[2] = x2; SB[3] = y2;
      float f = unflipf_dev(key);
      p.selScores[(size_t)t * NPRE + r] = 1.0 / (1.0 + exp(-(double)f));
    }
  }
}

// --- 5. fp64 pairwise IoU -> suppression bitmask (upper triangle) -----------
__global__ void k_iou(RPNParams p) {
  int bx = blockIdx.x;
  int t = bx / 20;
  int r0 = (bx % 20) * 100;
  __shared__ double X1[2000], Y1[2000], X2[2000], Y2[2000];
  const double* SB = p.selBoxes + (size_t)t * NPRE * 4;
  for (int i = threadIdx.x; i < NPRE; i += 256) {
    X1[i] = SB[i * 4 + 0]; Y1[i] = SB[i * 4 + 1];
    X2[i] = SB[i * 4 + 2]; Y2[i] = SB[i * 4 + 3];
  }
  __syncthreads();
  int wave = threadIdx.x >> 6, lane = threadIdx.x & 63;
  for (int i = r0 + wave; i < r0 + 100; i += 4) {
    double x1i = X1[i], y1i = Y1[i], x2i = X2[i], y2i = Y2[i];
    double ai = (x2i - x1i) * (y2i - y1i);
    unsigned int nz = 0;
    for (int k = 0; k < 32; k++) {
      int j = k * 64 + lane;
      bool pred = false;
      if (j > i && j < NPRE) {
        double x1j = X1[j], y1j = Y1[j], x2j = X2[j], y2j = Y2[j];
        double aj = (x2j - x1j) * (y2j - y1j);
        double lx = fmax(x1i, x1j), ly = fmax(y1i, y1j);
        double rx = fmin(x2i, x2j), ry = fmin(y2i, y2j);
        double w = fmax(rx - lx, 0.0), h = fmax(ry - ly, 0.0);
        double inter = w * h;
        double uni = fmax(ai + aj - inter, 1e-6);
        // pred <=> (inter/uni > 0.7) in fp64. Cross-mul filter; exact
        // division only within 1e-9 relative band of the boundary (the
        // fp64 rounding ambiguity band is ~1e-16 -- filter is 1e7x wider).
        double rhs = 0.7 * uni;
        if (fabs(inter - rhs) > 1e-9 * uni) {
          pred = inter > rhs;
        } else {
          pred = (inter / uni) > 0.7;
        }
      }
      unsigned long long word = __ballot(pred);
      if (lane == 0) p.mask[((size_t)t * NPRE + i) * 32 + k] = word;
      nz |= (word ? 1u : 0u) << k;
    }
    if (lane == 0) p.rowNZ[(size_t)t * NPRE + i] = nz;
  }
}

// --- 6. greedy NMS scan, register-resident, 1 wave per task -----------------
// Lane c owns chunk c (elements c*64..c*64+63): holds the 64x64 self-chunk
// suppression submatrix in 64 u64 registers, plus the running suppression
// word suppw for its chunk. Per chunk: broadcast sc, run fully-unrolled
// 64-step closure (pure VALU chain), broadcast keep word, then lanes j>c
// apply kept rows' cross-chunk mask words with 8 loads in flight.
__global__ __launch_bounds__(64, 1) void k_greedy(RPNParams p) {
  int t = blockIdx.x;
  int lane = threadIdx.x;  // 64 threads = 1 wave
  const unsigned long long* MK = p.mask + (size_t)t * NPRE * 32;
  const unsigned int* NZ = p.rowNZ + (size_t)t * NPRE;
  __shared__ unsigned int sNZ[2048];

  // stage rowNZ in LDS (coalesced)
  for (int k = 0; k < 32; k++) {
    int i = k * 64 + lane;
    sNZ[i] = (i < NPRE) ? NZ[i] : 0u;
  }

  // preload self-chunk submatrix: M[t2] = mask row (lane*64+t2), col-chunk lane
  unsigned long long M[64];
#pragma unroll
  for (int t2 = 0; t2 < 64; t2++) {
    int i = lane * 64 + t2;
    M[t2] = (i < NPRE && lane < 32) ? MK[(size_t)i * 32 + lane] : 0ull;
  }
  __syncthreads();

  unsigned long long suppw = 0ull, keepw = 0ull;
  for (int c = 0; c < 32; c++) {
    unsigned long long sc = __shfl(suppw, c);
    // fully-unrolled within-chunk greedy closure (only lane c's result used)
    unsigned long long tmp = sc, kc = 0ull;
#pragma unroll
    for (int t2 = 0; t2 < 64; t2++) {
      unsigned long long bit = 1ull << t2;
      if (!(tmp & bit)) {
        kc |= bit;
        tmp |= M[t2];
      }
    }
    unsigned long long kcc = __shfl(kc, c);
    unsigned long long tmpc = __shfl(tmp, c);
    if (lane == c) {
      suppw = tmpc;
      keepw = kcc;
    }
    // cross-chunk apply: lanes j in (c,32) OR in kept rows' word j.
    // Batch 8 kept rows so 8 loads are in flight.
    unsigned long long rem = kcc;
    bool applier = (lane > c) && (lane < 32);
    while (rem) {
      int rows[8];
#pragma unroll
      for (int q = 0; q < 8; q++) {
        if (rem) {
          int t2 = __ffsll((long long)rem) - 1;
          rem &= rem - 1;
          rows[q] = c * 64 + t2;
        } else {
          rows[q] = -1;
        }
      }
      unsigned long long v[8];
#pragma unroll
      for (int q = 0; q < 8; q++) {
        v[q] = (rows[q] >= 0 && applier && ((sNZ[rows[q]] >> lane) & 1u))
                   ? MK[(size_t)rows[q] * 32 + lane]
                   : 0ull;
      }
#pragma unroll
      for (int q = 0; q < 8; q++) suppw |= v[q];
    }
  }
  if (lane < 32) p.keeps[(size_t)t * 32 + lane] = keepw;
}

// --- 7. per-task re-rank: kept(+score) first (idx order), then -1 group -----
__global__ void k_post(RPNParams p) {
  int t = blockIdx.x;
  __shared__ unsigned long long kw[32], aw[32], bw[32];
  __shared__ unsigned int prefA[33], prefB[33];
  int tid = threadIdx.x;  // 256
  if (tid < 32) kw[tid] = p.keeps[(size_t)t * 32 + tid];
  __syncthreads();
  int wave = tid >> 6, lane = tid & 63;
  for (int ch = wave; ch < 32; ch += 4) {
    int i = ch * 64 + lane;
    bool inr = i < NPRE;
    bool kb = inr && ((kw[ch] >> lane) & 1ull);
    bool A = kb && (inr ? (p.selScores[(size_t)t * NPRE + i] > -0.5) : false);
    bool B = inr && !A;
    unsigned long long wa = __ballot(A);
    unsigned long long wb = __ballot(B);
    if (lane == 0) { aw[ch] = wa; bw[ch] = wb; }
  }
  __syncthreads();
  if (tid == 0) {
    unsigned int ca = 0, cb = 0;
    for (int w = 0; w < 32; w++) {
      prefA[w] = ca; ca += __popcll(aw[w]);
      prefB[w] = cb; cb += __popcll(bw[w]);
    }
    prefA[32] = ca; prefB[32] = cb;
  }
  __syncthreads();
  unsigned int KA = prefA[32];
  for (int i = tid; i < NPRE; i += 256) {
    int w = i >> 6, bpos = i & 63;
    unsigned long long below = (bpos == 0) ? 0ull : (~0ull >> (64 - bpos));
    bool kb = (kw[w] >> bpos) & 1ull;
    double s = p.selScores[(size_t)t * NPRE + i];
    bool A = kb && (s > -0.5);
    unsigned int slot;
    double outs;
    if (A) {
      slot = prefA[w] + (unsigned int)__popcll(aw[w] & below);
      outs = s;
    } else {
      slot = KA + prefB[w] + (unsigned int)__popcll(bw[w] & below);
      outs = -1.0;
    }
    if (slot < NPOST) {
      p.postScores[(size_t)t * NPOST + slot] = outs;
      const double* SB = p.selBoxes + ((size_t)t * NPRE + i) * 4;
      float* PB = p.postBoxes + ((size_t)t * NPOST + slot) * 4;
      PB[0] = (float)SB[0]; PB[1] = (float)SB[1];
      PB[2] = (float)SB[2]; PB[3] = (float)SB[3];
    }
  }
}

// --- 8a. final cross-level top-1000: sliced counting-rank -------------------
__global__ void k_finalA(RPNParams p) {
  int b = blockIdx.x >> 3;
  int s = blockIdx.x & 7;
  int j0 = s * 625;
  __shared__ unsigned long long kj[625];
  int tid = threadIdx.x;  // 1024
  for (int j = tid; j < 625; j += 1024) {
    int e = j0 + j;
    int l = e / 1000, slot = e % 1000;
    int t = l * 2 + b;
    kj[j] = flip64_dev(p.postScores[(size_t)t * NPOST + slot]);
  }
  __syncthreads();
  for (int e = tid; e < 5000; e += 1024) {
    int l = e / 1000, slot = e % 1000;
    int t = l * 2 + b;
    unsigned long long ke = flip64_dev(p.postScores[(size_t)t * NPOST + slot]);
    unsigned int r = 0;
    for (int j = 0; j < 625; j++) {
      unsigned long long v = kj[j];
      int jg = j0 + j;
      r += (v > ke || (v == ke && jg < e)) ? 1u : 0u;
    }
    p.partial[((size_t)b * 8 + s) * 5000 + e] = r;
  }
}

// --- 8b. reduce ranks, gather output boxes ----------------------------------
__global__ void k_finalB(RPNParams p) {
  int b = blockIdx.x;
  int tid = threadIdx.x;
  for (int e = tid; e < 5000; e += 1024) {
    unsigned int r = 0;
    for (int s = 0; s < 8; s++) r += p.partial[((size_t)b * 8 + s) * 5000 + e];
    if (r < NPOST) {
      int l = e / 1000, slot = e % 1000;
      int t = l * 2 + b;
      const float* PB = p.postBoxes + ((size_t)t * NPOST + slot) * 4;
      float* O = p.out + ((size_t)b * NPOST + r) * 4;
      O[0] = PB[0]; O[1] = PB[1]; O[2] = PB[2]; O[3] = PB[3];
    }
  }
}

extern "C" void kernel_launch(void* const* d_in, const int* in_sizes, int n_in,
                              void* d_out, int out_size, void* d_ws,
                              size_t ws_size, hipStream_t stream) {
  RPNParams p;
  // setup_inputs() dict order is interleaved (cls_i, bbox_i, anc_i per level);
  // detect defensively vs grouped order via in_sizes.
  bool interleaved = (n_in >= 2) && (in_sizes[1] == 4 * in_sizes[0]);
  for (int l = 0; l < 5; l++) {
    if (interleaved) {
      p.cls[l]  = (const float*)d_in[3 * l + 0];
      p.bbox[l] = (const float*)d_in[3 * l + 1];
      p.anc[l]  = (const float*)d_in[3 * l + 2];
    } else {
      p.cls[l]  = (const float*)d_in[l];
      p.bbox[l] = (const float*)d_in[5 + l];
      p.anc[l]  = (const float*)d_in[10 + l];
    }
  }
  char* w = (char*)d_ws;
  size_t off = 0;
  auto alloc = [&](size_t bytes) {
    off = (off + 255) & ~(size_t)255;
    void* r = w + off;
    off += bytes;
    return r;
  };
  p.hist      = (unsigned int*)alloc((size_t)10 * 65536 * 4);
  p.mainCount = (unsigned int*)alloc(10 * 4);
  p.candCount = (unsigned int*)alloc(10 * 4);
  size_t zbytes = off;  // zeroed region: hist + atomic counters
  p.Bstar      = (unsigned int*)alloc(10 * 4);
  p.mainEK     = (unsigned long long*)alloc((size_t)10 * 2048 * 8);
  p.candEK     = (unsigned long long*)alloc((size_t)10 * 8192 * 8);
  p.selBoxes   = (double*)alloc((size_t)10 * NPRE * 4 * 8);
  p.selScores  = (double*)alloc((size_t)10 * NPRE * 8);
  p.mask       = (unsigned long long*)alloc((size_t)10 * NPRE * 32 * 8);
  p.rowNZ      = (unsigned int*)alloc((size_t)10 * NPRE * 4);
  p.keeps      = (unsigned long long*)alloc((size_t)10 * 32 * 8);
  p.postScores = (double*)alloc((size_t)10 * NPOST * 8);
  p.postBoxes  = (float*)alloc((size_t)10 * NPOST * 4 * 4);
  p.partial    = (unsigned int*)alloc((size_t)16 * 5000 * 4);
  p.out = (float*)d_out;
  (void)ws_size; (void)out_size;

  hipMemsetAsync(d_ws, 0, zbytes, stream);
  k_hist<<<dim3(136), dim3(1024), 0, stream>>>(p);
  k_find<<<dim3(8), dim3(1024), 0, stream>>>(p);
  k_compact<<<dim3(136), dim3(1024), 0, stream>>>(p);
  k_assemble<<<dim3(10), dim3(1024), 0, stream>>>(p);
  k_iou<<<dim3(200), dim3(256), 0, stream>>>(p);
  k_greedy<<<dim3(10), dim3(64), 0, stream>>>(p);
  k_post<<<dim3(10), dim3(256), 0, stream>>>(p);
  k_finalA<<<dim3(16), dim3(1024), 0, stream>>>(p);
  k_finalB<<<dim3(2), dim3(1024), 0, stream>>>(p);
}